// Round 1
// 1323.026 us; speedup vs baseline: 5.7119x; 5.7119x over previous
//
#include <hip/hip_runtime.h>
#include <hip/hip_bf16.h>

#define B 2
#define CH 8
#define AM 8
#define NH 8
#define F 256
#define W 768
#define DH 32

#define WT 16
#define NWT (W / WT)     // 48
#define YPAD 20

#define QT 64
#define NQT (W / QT)     // 12
#define QSP 68
#define VSP 34
#define PLP 68

typedef __hip_bfloat16 bf16;
#define NE ((size_t)B * AM * F * W)   // 3,145,728

__device__ __forceinline__ float cvt(float v) { return v; }
__device__ __forceinline__ float cvt(bf16 v)  { return __bfloat162float(v); }
__device__ __forceinline__ void stv(float* p, float v) { *p = v; }
__device__ __forceinline__ void stv(bf16* p, float v)  { *p = __float2bfloat16(v); }

__device__ __forceinline__ float b2f_raw(unsigned short u) {
    union { unsigned int i; float f; } x; x.i = ((unsigned int)u) << 16; return x.f;
}
__device__ __forceinline__ unsigned short f2b_raw(float f) {
    union { bf16 h; unsigned short u; } x; x.h = __float2bfloat16(f); return x.u;
}

__device__ __forceinline__ float4 ld4(const float* p) { return *reinterpret_cast<const float4*>(p); }
__device__ __forceinline__ float4 ld4(const bf16* p) {
    ushort4 v = *reinterpret_cast<const ushort4*>(p);
    return make_float4(b2f_raw(v.x), b2f_raw(v.y), b2f_raw(v.z), b2f_raw(v.w));
}
__device__ __forceinline__ void st4(float* p, float a, float b, float c, float d) {
    *reinterpret_cast<float4*>(p) = make_float4(a, b, c, d);
}
__device__ __forceinline__ void st4(bf16* p, float a, float b, float c, float d) {
    ushort4 v; v.x = f2b_raw(a); v.y = f2b_raw(b); v.z = f2b_raw(c); v.w = f2b_raw(d);
    *reinterpret_cast<ushort4*>(p) = v;
}

// ---------------------------------------------------------------------------
// Input-dtype probe (unchanged from verified version). flag=1 -> bf16, 0 -> fp32
// ---------------------------------------------------------------------------
__global__ void detect_kernel(const void* __restrict__ xv, int* __restrict__ flag) {
    __shared__ int cnt[256];
    int tid = threadIdx.x;
    const bf16* xb = (const bf16*)xv;
    float v = fabsf(cvt(xb[2 * tid]));
    cnt[tid] = (v > 1e-3f && v < 1e3f) ? 1 : 0;
    __syncthreads();
    for (int st = 128; st > 0; st >>= 1) {
        if (tid < st) cnt[tid] += cnt[tid + st];
        __syncthreads();
    }
    if (tid == 0) flag[0] = (cnt[0] >= 128) ? 1 : 0;
}

// ---------------------------------------------------------------------------
// Fused conv3x3(+bias) -> positionwise linear (+rope), tiled.
// Block = (b, am, 16-wide w-tile), 256 threads.
// Output layout: (B, AM, F, W) fp32, feature g = h*32 + d.
// ---------------------------------------------------------------------------
template <typename T>
__device__ __forceinline__ void convpw_body(const T* __restrict__ x, const T* __restrict__ cw,
                                            const T* __restrict__ cb, const T* __restrict__ pw,
                                            float* __restrict__ out, int do_rope,
                                            float* ylds, float* wconv) {
    int blk = blockIdx.x;
    int wt = blk % NWT; int t = blk / NWT;
    int am = t % AM;    int b = t / AM;
    int w0 = wt * WT;
    int tid = threadIdx.x;

    if (tid < CH * 9) wconv[tid] = cvt(cw[am * CH * 9 + tid]);
    if (tid == 0) wconv[CH * 9] = cvt(cb[am]);
    __syncthreads();

    // ---- conv phase: lane -> w (coalesced x reads), f split across thread groups
    int wl = tid & (WT - 1);   // 0..15
    int fg = tid >> 4;         // 0..15
    float bias = wconv[CH * 9];
    float yacc[16];
    #pragma unroll
    for (int it = 0; it < 16; it++) yacc[it] = bias;

    for (int c = 0; c < CH; c++) {
        const T* xp = x + ((size_t)(b * CH + c) * F) * W;
        float wc[9];
        #pragma unroll
        for (int t9 = 0; t9 < 9; t9++) wc[t9] = wconv[c * 9 + t9];
        #pragma unroll
        for (int it = 0; it < 16; it++) {
            int f = fg * 16 + it;
            #pragma unroll
            for (int kh = 0; kh < 3; kh++) {
                int ff = f + kh - 1;
                if (ff < 0 || ff >= F) continue;
                const T* xr = xp + (size_t)ff * W;
                #pragma unroll
                for (int kw = 0; kw < 3; kw++) {
                    int ww = w0 + wl + kw - 1;
                    if (ww < 0 || ww >= W) continue;
                    yacc[it] += cvt(xr[ww]) * wc[kh * 3 + kw];
                }
            }
        }
    }
    #pragma unroll
    for (int it = 0; it < 16; it++) ylds[(fg * 16 + it) * YPAD + wl] = yacc[it];
    __syncthreads();

    // ---- positionwise GEMM: z[g][w] = sum_f pw[am][g][f] * y[f][w]
    int gi = tid >> 2;   // 0..63 -> g tile of 4
    int wj = tid & 3;    // 0..3  -> w tile of 4
    float acc[4][4];
    #pragma unroll
    for (int a0 = 0; a0 < 4; a0++)
        #pragma unroll
        for (int b0 = 0; b0 < 4; b0++) acc[a0][b0] = 0.f;

    const T* prow = pw + ((size_t)am * F + gi * 4) * F;
    for (int f = 0; f < F; f += 4) {
        float4 wv0 = ld4(prow + f);
        float4 wv1 = ld4(prow + F + f);
        float4 wv2 = ld4(prow + 2 * F + f);
        float4 wv3 = ld4(prow + 3 * F + f);
        #pragma unroll
        for (int kk = 0; kk < 4; kk++) {
            float4 yv = *reinterpret_cast<const float4*>(&ylds[(f + kk) * YPAD + wj * 4]);
            float a0 = reinterpret_cast<const float*>(&wv0)[kk];
            float a1 = reinterpret_cast<const float*>(&wv1)[kk];
            float a2 = reinterpret_cast<const float*>(&wv2)[kk];
            float a3 = reinterpret_cast<const float*>(&wv3)[kk];
            acc[0][0] += a0 * yv.x; acc[0][1] += a0 * yv.y; acc[0][2] += a0 * yv.z; acc[0][3] += a0 * yv.w;
            acc[1][0] += a1 * yv.x; acc[1][1] += a1 * yv.y; acc[1][2] += a1 * yv.z; acc[1][3] += a1 * yv.w;
            acc[2][0] += a2 * yv.x; acc[2][1] += a2 * yv.y; acc[2][2] += a2 * yv.z; acc[2][3] += a2 * yv.w;
            acc[3][0] += a3 * yv.x; acc[3][1] += a3 * yv.y; acc[3][2] += a3 * yv.z; acc[3][3] += a3 * yv.w;
        }
    }

    if (do_rope) {
        #pragma unroll
        for (int gg = 0; gg < 4; gg += 2) {
            int g = gi * 4 + gg;
            int d = g & (DH - 1);                       // even
            float inv = powf(10000.0f, -(float)d / (float)DH);
            #pragma unroll
            for (int ww = 0; ww < 4; ww++) {
                float ang = (float)(w0 + wj * 4 + ww) * inv;
                float cs = cosf(ang), sn = sinf(ang);
                float e = acc[gg][ww], o = acc[gg + 1][ww];
                acc[gg][ww]     = e * cs - o * sn;
                acc[gg + 1][ww] = o * cs + e * sn;
            }
        }
    }

    size_t obase = ((size_t)(b * AM + am) * F + gi * 4) * W + w0 + wj * 4;
    #pragma unroll
    for (int gg = 0; gg < 4; gg++)
        *reinterpret_cast<float4*>(&out[obase + (size_t)gg * W]) =
            make_float4(acc[gg][0], acc[gg][1], acc[gg][2], acc[gg][3]);
}

__global__ void __launch_bounds__(256)
convpw_kernel(const void* x, const void* cw, const void* cb, const void* pw,
              float* out, int do_rope, const int* __restrict__ flagp) {
    __shared__ float ylds[F * YPAD];
    __shared__ float wconv[76];
    if (*flagp)
        convpw_body<bf16>((const bf16*)x, (const bf16*)cw, (const bf16*)cb, (const bf16*)pw,
                          out, do_rope, ylds, wconv);
    else
        convpw_body<float>((const float*)x, (const float*)cw, (const float*)cb, (const float*)pw,
                           out, do_rope, ylds, wconv);
}

// ---------------------------------------------------------------------------
// Flash-style attention. Block = (mat, 64-row q-tile), 256 threads.
// q/k/v layout: [mat][d=0..31][w=0..767] fp32 (== (B,AM,F,W) with g=h*32+d).
// Writes qk (pre-softmax) and a (same layout as q; aliases q buffer).
// ---------------------------------------------------------------------------
template <typename T>
__device__ __forceinline__ void attn_body(const float* q, const float* k, const float* v,
                                          const T* __restrict__ prev, T* __restrict__ qk_out,
                                          float* aout,
                                          float* qs, float* ks, float* vsT, float* pl) {
    int blk = blockIdx.x;
    int qt = blk % NQT; int mat = blk / NQT;
    int q0 = qt * QT;
    int tid = threadIdx.x;
    int ti = tid >> 4;   // 0..15 : q-row group (4 rows)
    int tj = tid & 15;   // 0..15 : k-col group (4 cols)
    const float scale = 0.0625f;   // 1/sqrt(256)

    const float* qb = q + (size_t)mat * DH * W;
    const float* kb = k + (size_t)mat * DH * W;
    const float* vb = v + (size_t)mat * DH * W;

    // stage Q tile: qs[d][r]
    #pragma unroll
    for (int t2 = 0; t2 < 2; t2++) {
        int idx = tid + 256 * t2;
        int d = idx >> 4; int r4 = (idx & 15) << 2;
        *reinterpret_cast<float4*>(&qs[d * QSP + r4]) =
            *reinterpret_cast<const float4*>(&qb[(size_t)d * W + q0 + r4]);
    }

    float m[4], l[4], ov[4][2];
    #pragma unroll
    for (int rr = 0; rr < 4; rr++) { m[rr] = -1e30f; l[rr] = 0.f; ov[rr][0] = 0.f; ov[rr][1] = 0.f; }

    for (int kc = 0; kc < NQT; kc++) {
        int k0 = kc * QT;
        // stage K tile: ks[d][c]
        #pragma unroll
        for (int t2 = 0; t2 < 2; t2++) {
            int idx = tid + 256 * t2;
            int d = idx >> 4; int r4 = (idx & 15) << 2;
            *reinterpret_cast<float4*>(&ks[d * QSP + r4]) =
                *reinterpret_cast<const float4*>(&kb[(size_t)d * W + k0 + r4]);
        }
        // stage V tile transposed: vsT[c][d]
        {
            int d = tid >> 3; int k8 = (tid & 7) << 3;
            float4 a0 = *reinterpret_cast<const float4*>(&vb[(size_t)d * W + k0 + k8]);
            float4 a1 = *reinterpret_cast<const float4*>(&vb[(size_t)d * W + k0 + k8 + 4]);
            vsT[(k8 + 0) * VSP + d] = a0.x;
            vsT[(k8 + 1) * VSP + d] = a0.y;
            vsT[(k8 + 2) * VSP + d] = a0.z;
            vsT[(k8 + 3) * VSP + d] = a0.w;
            vsT[(k8 + 4) * VSP + d] = a1.x;
            vsT[(k8 + 5) * VSP + d] = a1.y;
            vsT[(k8 + 6) * VSP + d] = a1.z;
            vsT[(k8 + 7) * VSP + d] = a1.w;
        }
        __syncthreads();

        // S = Q.K^T (4x4 register tile)
        float s[4][4];
        #pragma unroll
        for (int rr = 0; rr < 4; rr++) { s[rr][0] = 0.f; s[rr][1] = 0.f; s[rr][2] = 0.f; s[rr][3] = 0.f; }
        #pragma unroll 8
        for (int d = 0; d < DH; d++) {
            float4 qv = *reinterpret_cast<const float4*>(&qs[d * QSP + ti * 4]);
            float4 kv = *reinterpret_cast<const float4*>(&ks[d * QSP + tj * 4]);
            s[0][0] += qv.x * kv.x; s[0][1] += qv.x * kv.y; s[0][2] += qv.x * kv.z; s[0][3] += qv.x * kv.w;
            s[1][0] += qv.y * kv.x; s[1][1] += qv.y * kv.y; s[1][2] += qv.y * kv.z; s[1][3] += qv.y * kv.w;
            s[2][0] += qv.z * kv.x; s[2][1] += qv.z * kv.y; s[2][2] += qv.z * kv.z; s[2][3] += qv.z * kv.w;
            s[3][0] += qv.w * kv.x; s[3][1] += qv.w * kv.y; s[3][2] += qv.w * kv.z; s[3][3] += qv.w * kv.w;
        }

        // scale + prev, write qk
        #pragma unroll
        for (int rr = 0; rr < 4; rr++) {
            size_t off = ((size_t)mat * W + (q0 + ti * 4 + rr)) * (size_t)W + k0 + tj * 4;
            float4 pv = ld4(prev + off);
            s[rr][0] = s[rr][0] * scale + pv.x;
            s[rr][1] = s[rr][1] * scale + pv.y;
            s[rr][2] = s[rr][2] * scale + pv.z;
            s[rr][3] = s[rr][3] * scale + pv.w;
            st4(qk_out + off, s[rr][0], s[rr][1], s[rr][2], s[rr][3]);
        }

        // online softmax (row reductions across the 16 tj lanes)
        #pragma unroll
        for (int rr = 0; rr < 4; rr++) {
            float lm = fmaxf(fmaxf(s[rr][0], s[rr][1]), fmaxf(s[rr][2], s[rr][3]));
            lm = fmaxf(lm, __shfl_xor(lm, 1));
            lm = fmaxf(lm, __shfl_xor(lm, 2));
            lm = fmaxf(lm, __shfl_xor(lm, 4));
            lm = fmaxf(lm, __shfl_xor(lm, 8));
            float mn = fmaxf(m[rr], lm);
            float fs = __expf(m[rr] - mn);
            m[rr] = mn; l[rr] *= fs; ov[rr][0] *= fs; ov[rr][1] *= fs;
            float p0 = __expf(s[rr][0] - mn);
            float p1 = __expf(s[rr][1] - mn);
            float p2 = __expf(s[rr][2] - mn);
            float p3 = __expf(s[rr][3] - mn);
            l[rr] += p0 + p1 + p2 + p3;
            *reinterpret_cast<float4*>(&pl[(ti * 4 + rr) * PLP + tj * 4]) = make_float4(p0, p1, p2, p3);
        }
        __syncthreads();

        // O += P.V  (thread covers rows 4*ti.., d = 2*tj..2*tj+1)
        #pragma unroll 4
        for (int c4 = 0; c4 < QT; c4 += 4) {
            float4 pr0 = *reinterpret_cast<const float4*>(&pl[(ti * 4 + 0) * PLP + c4]);
            float4 pr1 = *reinterpret_cast<const float4*>(&pl[(ti * 4 + 1) * PLP + c4]);
            float4 pr2 = *reinterpret_cast<const float4*>(&pl[(ti * 4 + 2) * PLP + c4]);
            float4 pr3 = *reinterpret_cast<const float4*>(&pl[(ti * 4 + 3) * PLP + c4]);
            #pragma unroll
            for (int kk = 0; kk < 4; kk++) {
                float2 vv = *reinterpret_cast<const float2*>(&vsT[(c4 + kk) * VSP + tj * 2]);
                float pa0 = reinterpret_cast<const float*>(&pr0)[kk];
                float pa1 = reinterpret_cast<const float*>(&pr1)[kk];
                float pa2 = reinterpret_cast<const float*>(&pr2)[kk];
                float pa3 = reinterpret_cast<const float*>(&pr3)[kk];
                ov[0][0] += pa0 * vv.x; ov[0][1] += pa0 * vv.y;
                ov[1][0] += pa1 * vv.x; ov[1][1] += pa1 * vv.y;
                ov[2][0] += pa2 * vv.x; ov[2][1] += pa2 * vv.y;
                ov[3][0] += pa3 * vv.x; ov[3][1] += pa3 * vv.y;
            }
        }
        __syncthreads();
    }

    // finalize: denom reduce across tj lanes, stage O to LDS, coalesced store
    #pragma unroll
    for (int rr = 0; rr < 4; rr++) {
        float lv = l[rr];
        lv += __shfl_xor(lv, 1);
        lv += __shfl_xor(lv, 2);
        lv += __shfl_xor(lv, 4);
        lv += __shfl_xor(lv, 8);
        float inv = 1.0f / lv;
        pl[(ti * 4 + rr) * VSP + tj * 2]     = ov[rr][0] * inv;
        pl[(ti * 4 + rr) * VSP + tj * 2 + 1] = ov[rr][1] * inv;
    }
    __syncthreads();
    {
        int d = tid >> 3; int q8 = (tid & 7) << 3;
        float r0[8];
        #pragma unroll
        for (int qq = 0; qq < 8; qq++) r0[qq] = pl[(q8 + qq) * VSP + d];
        size_t ob = ((size_t)mat * DH + d) * W + q0 + q8;
        *reinterpret_cast<float4*>(&aout[ob])     = make_float4(r0[0], r0[1], r0[2], r0[3]);
        *reinterpret_cast<float4*>(&aout[ob + 4]) = make_float4(r0[4], r0[5], r0[6], r0[7]);
    }
}

__global__ void __launch_bounds__(256)
attn_kernel(const float* q, const float* k, const float* v, const void* prev,
            void* d_out, float* aout, const int* __restrict__ flagp) {
    __shared__ float qs[DH * QSP];
    __shared__ float ks[DH * QSP];
    __shared__ float vsT[QT * VSP];
    __shared__ float pl[QT * PLP];
    if (*flagp) {
        bf16* qk = (bf16*)d_out + NE;
        attn_body<bf16>(q, k, v, (const bf16*)prev, qk, aout, qs, ks, vsT, pl);
    } else {
        float* qk = (float*)d_out + NE;
        attn_body<float>(q, k, v, (const float*)prev, qk, aout, qs, ks, vsT, pl);
    }
}

// ---------------------------------------------------------------------------
// o_proj positionwise GEMM: z2[b][c][g][w] = sum_f o_pw[c][g][f] * col[c][f][w]
// col: c<8 -> x, c>=8 -> a (both (.,F,W) contiguous). Block=(b,c,w-tile).
// ---------------------------------------------------------------------------
template <typename T>
__device__ __forceinline__ void pwo_body(const T* __restrict__ x, const float* a,
                                         const T* __restrict__ opw, float* __restrict__ z2,
                                         float* ylds) {
    int blk = blockIdx.x;
    int wt = blk % NWT; int t = blk / NWT;
    int c = t & 15;     int b = t >> 4;
    int w0 = wt * WT;
    int tid = threadIdx.x;

    if (c < CH) {
        const T* src = x + ((size_t)(b * CH + c) * F) * W;
        #pragma unroll
        for (int rep = 0; rep < 4; rep++) {
            int idx = tid + 256 * rep;
            int f = idx >> 2; int wq = (idx & 3) << 2;
            float4 vv = ld4(src + (size_t)f * W + w0 + wq);
            *reinterpret_cast<float4*>(&ylds[f * YPAD + wq]) = vv;
        }
    } else {
        const float* src = a + ((size_t)(b * AM + (c - CH)) * F) * W;
        #pragma unroll
        for (int rep = 0; rep < 4; rep++) {
            int idx = tid + 256 * rep;
            int f = idx >> 2; int wq = (idx & 3) << 2;
            *reinterpret_cast<float4*>(&ylds[f * YPAD + wq]) =
                *reinterpret_cast<const float4*>(&src[(size_t)f * W + w0 + wq]);
        }
    }
    __syncthreads();

    int gi = tid >> 2;
    int wj = tid & 3;
    float acc[4][4];
    #pragma unroll
    for (int a0 = 0; a0 < 4; a0++)
        #pragma unroll
        for (int b0 = 0; b0 < 4; b0++) acc[a0][b0] = 0.f;

    const T* prow = opw + ((size_t)c * F + gi * 4) * F;
    for (int f = 0; f < F; f += 4) {
        float4 wv0 = ld4(prow + f);
        float4 wv1 = ld4(prow + F + f);
        float4 wv2 = ld4(prow + 2 * F + f);
        float4 wv3 = ld4(prow + 3 * F + f);
        #pragma unroll
        for (int kk = 0; kk < 4; kk++) {
            float4 yv = *reinterpret_cast<const float4*>(&ylds[(f + kk) * YPAD + wj * 4]);
            float a0 = reinterpret_cast<const float*>(&wv0)[kk];
            float a1 = reinterpret_cast<const float*>(&wv1)[kk];
            float a2 = reinterpret_cast<const float*>(&wv2)[kk];
            float a3 = reinterpret_cast<const float*>(&wv3)[kk];
            acc[0][0] += a0 * yv.x; acc[0][1] += a0 * yv.y; acc[0][2] += a0 * yv.z; acc[0][3] += a0 * yv.w;
            acc[1][0] += a1 * yv.x; acc[1][1] += a1 * yv.y; acc[1][2] += a1 * yv.z; acc[1][3] += a1 * yv.w;
            acc[2][0] += a2 * yv.x; acc[2][1] += a2 * yv.y; acc[2][2] += a2 * yv.z; acc[2][3] += a2 * yv.w;
            acc[3][0] += a3 * yv.x; acc[3][1] += a3 * yv.y; acc[3][2] += a3 * yv.z; acc[3][3] += a3 * yv.w;
        }
    }

    size_t obase = ((size_t)(b * 16 + c) * F + gi * 4) * W + w0 + wj * 4;
    #pragma unroll
    for (int gg = 0; gg < 4; gg++)
        *reinterpret_cast<float4*>(&z2[obase + (size_t)gg * W]) =
            make_float4(acc[gg][0], acc[gg][1], acc[gg][2], acc[gg][3]);
}

__global__ void __launch_bounds__(256)
pwo_kernel(const void* x, const float* a, const void* o_pw, float* z2,
           const int* __restrict__ flagp) {
    __shared__ float ylds[F * YPAD];
    if (*flagp)
        pwo_body<bf16>((const bf16*)x, a, (const bf16*)o_pw, z2, ylds);
    else
        pwo_body<float>((const float*)x, a, (const float*)o_pw, z2, ylds);
}

// ---------------------------------------------------------------------------
// Depthwise channel mix: out[b][dch][g][w] = sum_c o_dw[dch][c] * z2[b][c][g][w]
// ---------------------------------------------------------------------------
template <typename T>
__device__ __forceinline__ void mix_body(const float* __restrict__ z2, const T* __restrict__ odw,
                                         T* __restrict__ outp, float* sdw) {
    int tid = threadIdx.x;
    if (tid < CH * 16) sdw[tid] = cvt(odw[tid]);
    __syncthreads();
    int blk = blockIdx.x;
    int g = blk % F; int b = blk / F;
    for (int wi = 0; wi < 3; wi++) {
        int w = wi * 256 + tid;
        float zin[16];
        #pragma unroll
        for (int c = 0; c < 16; c++) zin[c] = z2[((size_t)(b * 16 + c) * F + g) * W + w];
        #pragma unroll
        for (int dch = 0; dch < CH; dch++) {
            float o = 0.f;
            #pragma unroll
            for (int c = 0; c < 16; c++) o += sdw[dch * 16 + c] * zin[c];
            stv(&outp[((size_t)(b * CH + dch) * F + g) * W + w], o);
        }
    }
}

__global__ void __launch_bounds__(256)
mix_kernel(const float* z2, const void* o_dw, void* d_out, const int* __restrict__ flagp) {
    __shared__ float sdw[CH * 16];
    if (*flagp)
        mix_body<bf16>(z2, (const bf16*)o_dw, (bf16*)d_out, sdw);
    else
        mix_body<float>(z2, (const float*)o_dw, (float*)d_out, sdw);
}

extern "C" void kernel_launch(void* const* d_in, const int* in_sizes, int n_in,
                              void* d_out, int out_size, void* d_ws, size_t ws_size,
                              hipStream_t stream) {
    const void* x     = d_in[0];
    const void* prev  = d_in[1];
    const void* q_cw  = d_in[2];
    const void* q_cb  = d_in[3];
    const void* q_pw  = d_in[4];
    const void* k_cw  = d_in[5];
    const void* k_cb  = d_in[6];
    const void* k_pw  = d_in[7];
    const void* v_cw  = d_in[8];
    const void* v_cb  = d_in[9];
    const void* v_pw  = d_in[10];
    const void* o_pw  = d_in[11];
    const void* o_dw  = d_in[12];

    int*   flag = (int*)d_ws;
    float* qb = (float*)d_ws + 64;        // 3*NE fp32 total = 37.75 MB
    float* kb = qb + NE;
    float* vb = kb + NE;
    float* ab = qb;                       // a aliases q (block-exclusive tiles)
    float* z2 = kb;                       // z2 (2*NE) aliases k+v (dead after attn)

    detect_kernel<<<1, 256, 0, stream>>>(x, flag);

    convpw_kernel<<<B * AM * NWT, 256, 0, stream>>>(x, q_cw, q_cb, q_pw, qb, 1, flag);
    convpw_kernel<<<B * AM * NWT, 256, 0, stream>>>(x, k_cw, k_cb, k_pw, kb, 1, flag);
    convpw_kernel<<<B * AM * NWT, 256, 0, stream>>>(x, v_cw, v_cb, v_pw, vb, 0, flag);

    attn_kernel<<<B * AM * NH * NQT, 256, 0, stream>>>(qb, kb, vb, prev, d_out, ab, flag);

    pwo_kernel<<<B * 16 * NWT, 256, 0, stream>>>(x, ab, o_pw, z2, flag);
    mix_kernel<<<B * F, 256, 0, stream>>>(z2, o_dw, d_out, flag);
}